// Round 8
// baseline (394.509 us; speedup 1.0000x reference)
//
#include <hip/hip_runtime.h>
#include <math.h>

#define EPS_F 1e-5f
static constexpr int BATCH = 4096;

// ---------------------------------------------------------------------------
// K1: conv1 3x3 SAME (1->8) per batch element + bn1 stats (pre-pool) + 2x2
// maxpool of RAW conv output. Pooling done in-register via shuffles
// (vertical pair = lane^32 since y0 parity is lane bit 5; horizontal pair =
// lane^1), compacted through a small LDS buffer for coalesced output.
//  - conv bias skipped: bn(h+c) == bn(h) for per-channel constant c.
//  - pooling raw is valid: relu(bn(x)) is monotone (scale > 0).
__global__ __launch_bounds__(256) void k1(const float* __restrict__ x,
                                          const float* __restrict__ w1,
                                          float* __restrict__ pooled1,
                                          float* __restrict__ p1sum,
                                          float* __restrict__ p1sq) {
    __shared__ __align__(16) float xs[34 * 34];   // zero-padded input tile (4.6 KB)
    __shared__ float w1s[72];
    __shared__ __align__(16) float ps[2048];      // pooled staging, coalesced write (8 KB)
    __shared__ float rsum[4][8], rsq[4][8];

    const int b = blockIdx.x, t = threadIdx.x;
    for (int j = t; j < 34 * 34; j += 256) xs[j] = 0.f;
    if (t < 72) w1s[t] = w1[t];
    __syncthreads();
    {
        float4 v4 = reinterpret_cast<const float4*>(x + (size_t)b * 1024)[t];
        int e = t * 4, y = e >> 5, xx = e & 31;
        float* d = &xs[(y + 1) * 34 + xx + 1];
        d[0] = v4.x; d[1] = v4.y; d[2] = v4.z; d[3] = v4.w;
    }
    __syncthreads();

    // thread = (col, y0); covers rows y0+8k, k=0..3, all 8 channels
    const int col = t & 31, y0 = t >> 5;
    float acc[4][8];
#pragma unroll
    for (int k = 0; k < 4; ++k)
#pragma unroll
        for (int c = 0; c < 8; ++c) acc[k][c] = 0.f;

#pragma unroll
    for (int ky = 0; ky < 3; ++ky)
#pragma unroll
        for (int kx = 0; kx < 3; ++kx) {
            float w[8];
#pragma unroll
            for (int c = 0; c < 8; ++c) w[c] = w1s[c * 9 + ky * 3 + kx];
#pragma unroll
            for (int k = 0; k < 4; ++k) {
                float xv = xs[(y0 + 8 * k + ky) * 34 + col + kx];
#pragma unroll
                for (int c = 0; c < 8; ++c) acc[k][c] = fmaf(w[c], xv, acc[k][c]);
            }
        }

    // bn1 stats over the full 32x32 (pre-pool)
    float s[8], q[8];
#pragma unroll
    for (int c = 0; c < 8; ++c) { s[c] = 0.f; q[c] = 0.f; }
#pragma unroll
    for (int k = 0; k < 4; ++k)
#pragma unroll
        for (int c = 0; c < 8; ++c) { s[c] += acc[k][c]; q[c] += acc[k][c] * acc[k][c]; }
#pragma unroll
    for (int d = 1; d < 64; d <<= 1)
#pragma unroll
        for (int c = 0; c < 8; ++c) {
            s[c] += __shfl_xor(s[c], d, 64);
            q[c] += __shfl_xor(q[c], d, 64);
        }
    const int wid = t >> 6, lane = t & 63;
    if (lane == 0)
#pragma unroll
        for (int c = 0; c < 8; ++c) { rsum[wid][c] = s[c]; rsq[wid][c] = q[c]; }

    // 2x2 maxpool in-register: wave wid holds y0 in {2*wid, 2*wid+1};
    // vertical pair is lane^32 (flips y0 parity), horizontal pair lane^1.
    // Pooled row py = 4k + wid; valid on lanes with y0 even && col even.
#pragma unroll
    for (int k = 0; k < 4; ++k)
#pragma unroll
        for (int c = 0; c < 8; ++c) {
            float vm = fmaxf(acc[k][c], __shfl_xor(acc[k][c], 32, 64));
            float hm = fmaxf(vm, __shfl_xor(vm, 1, 64));
            if ((lane & 33) == 0)
                ps[c * 256 + (4 * k + wid) * 16 + (col >> 1)] = hm;
        }
    __syncthreads();

    if (t < 8) {
        p1sum[t * BATCH + b] = rsum[0][t] + rsum[1][t] + rsum[2][t] + rsum[3][t];
        p1sq [t * BATCH + b] = rsq [0][t] + rsq [1][t] + rsq [2][t] + rsq [3][t];
    }
    // coalesced pooled1 write: [8c][16py][16px] flat, 8 floats per thread
    float4 o0 = *reinterpret_cast<const float4*>(&ps[t * 8]);
    float4 o1 = *reinterpret_cast<const float4*>(&ps[t * 8 + 4]);
    float4* dst = reinterpret_cast<float4*>(&pooled1[(size_t)b * 2048 + t * 8]);
    dst[0] = o0; dst[1] = o1;
}

// ---------------------------------------------------------------------------
// Finalize BN params from per-block partials: scale = g*rsqrt(var+eps),
// shift = beta - mean*scale.  One block per channel.
__global__ __launch_bounds__(256) void k_bnfin(const float* __restrict__ psum,
                                               const float* __restrict__ psq,
                                               const float* __restrict__ g,
                                               const float* __restrict__ beta,
                                               float* __restrict__ scale,
                                               float* __restrict__ shift,
                                               float invN) {
    const int ch = blockIdx.x, t = threadIdx.x;
    float s = 0.f, q = 0.f;
    for (int i = t; i < BATCH; i += 256) {
        s += psum[ch * BATCH + i];
        q += psq [ch * BATCH + i];
    }
    __shared__ float rs[256], rq[256];
    rs[t] = s; rq[t] = q;
    __syncthreads();
    for (int d = 128; d > 0; d >>= 1) {
        if (t < d) { rs[t] += rs[t + d]; rq[t] += rq[t + d]; }
        __syncthreads();
    }
    if (t == 0) {
        float mean = rs[0] * invN;
        float var  = rq[0] * invN - mean * mean;
        float sc   = g[ch] * rsqrtf(var + EPS_F);
        scale[ch] = sc;
        shift[ch] = beta[ch] - mean * sc;
    }
}

// ---------------------------------------------------------------------------
// bn2-stats + 2x2 pool + store helper for one local oc of k3.
// acc: 16 x-values for row y. Reduction over the 16 y-lanes of this oc-group
// (shfl_xor d<16 stays in the aligned 16-lane group). Vertical pool pair is
// lane^1 (y parity).
__device__ __forceinline__ void k3_stats_pool(const float* acc, int oc, int b, int y,
                                              float* __restrict__ pooled2,
                                              float* __restrict__ p2sum,
                                              float* __restrict__ p2sq) {
    float s = 0.f, q = 0.f;
#pragma unroll
    for (int xx = 0; xx < 16; ++xx) { s += acc[xx]; q += acc[xx] * acc[xx]; }
#pragma unroll
    for (int d = 1; d < 16; d <<= 1) { s += __shfl_xor(s, d, 64); q += __shfl_xor(q, d, 64); }
    float vm[16];
#pragma unroll
    for (int xx = 0; xx < 16; ++xx) vm[xx] = fmaxf(acc[xx], __shfl_xor(acc[xx], 1, 64));
    if ((y & 1) == 0) {
        float4 h0 = make_float4(fmaxf(vm[0], vm[1]),  fmaxf(vm[2], vm[3]),
                                fmaxf(vm[4], vm[5]),  fmaxf(vm[6], vm[7]));
        float4 h1 = make_float4(fmaxf(vm[8], vm[9]),  fmaxf(vm[10], vm[11]),
                                fmaxf(vm[12], vm[13]), fmaxf(vm[14], vm[15]));
        float4* d2 = reinterpret_cast<float4*>(
            &pooled2[(size_t)b * 1024 + oc * 64 + (y >> 1) * 8]);
        d2[0] = h0; d2[1] = h1;
    }
    if (y == 0) { p2sum[oc * BATCH + b] = s; p2sq[oc * BATCH + b] = q; }
}

// ---------------------------------------------------------------------------
// K3: bn1+relu on pooled1raw, conv2 3x3 SAME (8->16), bn2 stats (pre-pool),
// 2x2 maxpool of RAW conv2.  One WAVE per batch element (4 elems / block);
// each thread owns 4 output channels x 16 x-positions for one row y.
// This cuts LDS read instructions 4x vs a 4-wave-per-element mapping:
// 120 row-b128 + 72 weight-b128 per element (weights pre-transposed in LDS
// to [ic,ky,kx][oc] so 4 consecutive oc load as one b128).
__global__ __launch_bounds__(256) void k3(const float* __restrict__ pooled1,
                                          const float* __restrict__ w2,
                                          const float* __restrict__ s1,
                                          const float* __restrict__ sh1,
                                          float* __restrict__ pooled2,
                                          float* __restrict__ p2sum,
                                          float* __restrict__ p2sq) {
    __shared__ __align__(16) float a1s[4][2880];   // per elem: [ic][y+1][x+1], stride 20 (46 KB)
    __shared__ __align__(16) float w2t[1152];      // [(ic*9+ky*3+kx)*16 + oc] (4.6 KB)
    const int t = threadIdx.x;
    const int e = t >> 6, lane = t & 63;
    const int o = lane >> 4, y = lane & 15;   // o = oc-quad (ocs 4o..4o+3), y = row
    const int b = blockIdx.x * 4 + e;

    {   // zero all padded tiles (vectorized)
        float4 z = make_float4(0.f, 0.f, 0.f, 0.f);
        float* base = &a1s[0][0];
        for (int j = t; j < 2880; j += 256)          // 2880 float4 = 11520 floats
            *reinterpret_cast<float4*>(&base[j * 4]) = z;
    }
    for (int j = t; j < 1152; j += 256) {            // transpose weights
        int oc = j / 72, r = j - oc * 72;            // r = ic*9 + ky*3 + kx
        w2t[r * 16 + oc] = w2[j];
    }
    __syncthreads();

    float s1r[8], sh1r[8];
#pragma unroll
    for (int c = 0; c < 8; ++c) { s1r[c] = s1[c]; sh1r[c] = sh1[c]; }

    {   // stage own element's interior with bn1+relu (wave-private)
        const float* src = pooled1 + (size_t)b * 2048;
        float* dst = &a1s[e][0];
#pragma unroll
        for (int i = 0; i < 32; ++i) {
            int idx = i * 64 + lane;
            int c = idx >> 8, rem = idx & 255, py = rem >> 4, px = rem & 15;
            float v = fmaxf(fmaf(src[idx], s1r[c], sh1r[c]), 0.f);
            dst[c * 360 + (py + 1) * 20 + (px + 1)] = v;
        }
    }
    __syncthreads();

    float acc0[16], acc1[16], acc2[16], acc3[16];
#pragma unroll
    for (int i = 0; i < 16; ++i) { acc0[i] = 0.f; acc1[i] = 0.f; acc2[i] = 0.f; acc3[i] = 0.f; }

#pragma unroll
    for (int ic = 0; ic < 8; ++ic)
#pragma unroll
        for (int ky = 0; ky < 3; ++ky) {
            const float* row = &a1s[e][ic * 360 + (y + ky) * 20];
            float r[20];
#pragma unroll
            for (int j = 0; j < 5; ++j)
                *reinterpret_cast<float4*>(&r[4 * j]) =
                    *reinterpret_cast<const float4*>(&row[4 * j]);
#pragma unroll
            for (int kx = 0; kx < 3; ++kx) {
                float4 w4 = *reinterpret_cast<const float4*>(
                    &w2t[(ic * 9 + ky * 3 + kx) * 16 + o * 4]);
#pragma unroll
                for (int xx = 0; xx < 16; ++xx) {
                    float rv = r[xx + kx];
                    acc0[xx] = fmaf(w4.x, rv, acc0[xx]);
                    acc1[xx] = fmaf(w4.y, rv, acc1[xx]);
                    acc2[xx] = fmaf(w4.z, rv, acc2[xx]);
                    acc3[xx] = fmaf(w4.w, rv, acc3[xx]);
                }
            }
        }

    k3_stats_pool(acc0, o * 4 + 0, b, y, pooled2, p2sum, p2sq);
    k3_stats_pool(acc1, o * 4 + 1, b, y, pooled2, p2sum, p2sq);
    k3_stats_pool(acc2, o * 4 + 2, b, y, pooled2, p2sum, p2sq);
    k3_stats_pool(acc3, o * 4 + 3, b, y, pooled2, p2sum, p2sq);
}

// ---------------------------------------------------------------------------
// K5: bn2+relu on pooled2raw, encode = mean, quantum circuit collapsed to
// q = (cos e, cos e, cos^2 e, cos^2 e)  (RZ phases cancel in |amp|^2; CNOT
// chain applied twice maps bits to (b0,b1,b0^b2,b1^b3), i.i.d. Bernoulli),
// then fc.  One 64-lane wave per batch element.
__global__ __launch_bounds__(256) void k5(const float* __restrict__ pooled2,
                                          const float* __restrict__ s2,
                                          const float* __restrict__ sh2,
                                          const float* __restrict__ fcw,
                                          const float* __restrict__ fcb,
                                          float* __restrict__ outbuf) {
    const int t = threadIdx.x, lane = t & 63;
    const int b = blockIdx.x * 4 + (t >> 6);
    const float* p = pooled2 + (size_t)b * 1024;
    float sum = 0.f;
#pragma unroll
    for (int i = 0; i < 16; ++i) {       // element (i*64+lane) has channel i
        float v = p[i * 64 + lane];
        v = fmaxf(fmaf(v, s2[i], sh2[i]), 0.f);
        sum += v;
    }
#pragma unroll
    for (int d = 1; d < 64; d <<= 1) sum += __shfl_xor(sum, d, 64);
    if (lane < 4) {
        float e = sum * (1.f / 1024.f);
        float z = cosf(e), z2 = z * z;
        int j = lane;
        float o = fcb[j] + z * (fcw[j * 4 + 0] + fcw[j * 4 + 1])
                         + z2 * (fcw[j * 4 + 2] + fcw[j * 4 + 3]);
        outbuf[(size_t)b * 4 + j] = o;
    }
}

// ---------------------------------------------------------------------------
// K67: bn3 stats + apply, fused. 16 blocks; each computes the full stats
// redundantly (outbuf is 64 KB, L2-resident) then applies to its slice.
__global__ __launch_bounds__(256) void k67(const float* __restrict__ outbuf,
                                           const float* __restrict__ g3,
                                           const float* __restrict__ b3,
                                           float* __restrict__ out) {
    const int t = threadIdx.x, j = t & 3;
    float s = 0.f, q = 0.f;
    for (int i = t >> 2; i < BATCH; i += 64) {
        float v = outbuf[i * 4 + j];
        s += v; q += v * v;
    }
    __shared__ float rs[256], rq[256];
    __shared__ float sc[4], sh[4];
    rs[t] = s; rq[t] = q;
    __syncthreads();
    for (int d = 128; d >= 4; d >>= 1) {   // d%4==0 keeps same feature j
        if (t < d) { rs[t] += rs[t + d]; rq[t] += rq[t + d]; }
        __syncthreads();
    }
    if (t < 4) {
        float mean = rs[t] * (1.f / BATCH);
        float var  = rq[t] * (1.f / BATCH) - mean * mean;
        float s3   = g3[t] * rsqrtf(var + EPS_F);
        sc[t] = s3;
        sh[t] = b3[t] - mean * s3;
    }
    __syncthreads();
    int base = blockIdx.x * 1024 + t * 4;   // 16 blocks x 1024 = 16384 elems
    float4 v = *reinterpret_cast<const float4*>(&outbuf[base]);
    float4 r;
    r.x = fmaf(v.x, sc[0], sh[0]);
    r.y = fmaf(v.y, sc[1], sh[1]);
    r.z = fmaf(v.z, sc[2], sh[2]);
    r.w = fmaf(v.w, sc[3], sh[3]);
    *reinterpret_cast<float4*>(&out[base]) = r;
}

extern "C" void kernel_launch(void* const* d_in, const int* in_sizes, int n_in,
                              void* d_out, int out_size, void* d_ws, size_t ws_size,
                              hipStream_t stream) {
    const float* x   = (const float*)d_in[0];
    const float* w1  = (const float*)d_in[1];
    // d_in[2] conv1_b: cancels in bn1
    const float* g1  = (const float*)d_in[3];
    const float* b1  = (const float*)d_in[4];
    const float* w2  = (const float*)d_in[5];
    // d_in[6] conv2_b: cancels in bn2
    const float* g2  = (const float*)d_in[7];
    const float* b2  = (const float*)d_in[8];
    // d_in[9] rz_angles: diagonal phases, cancel in probabilities
    const float* fcw = (const float*)d_in[10];
    const float* fcb = (const float*)d_in[11];
    const float* g3  = (const float*)d_in[12];
    const float* b3  = (const float*)d_in[13];

    float* ws      = (float*)d_ws;
    float* pooled1 = ws;                                 // 4096*2048
    float* pooled2 = pooled1 + (size_t)BATCH * 2048;     // 4096*1024
    float* p1sum   = pooled2 + (size_t)BATCH * 1024;     // 8*4096
    float* p1sq    = p1sum + 8 * BATCH;
    float* p2sum   = p1sq  + 8 * BATCH;                  // 16*4096
    float* p2sq    = p2sum + 16 * BATCH;
    float* s1      = p2sq  + 16 * BATCH;                 // 8
    float* sh1     = s1 + 8;
    float* s2      = sh1 + 8;                            // 16
    float* sh2     = s2 + 16;
    float* outbuf  = sh2 + 16;                           // 4096*4
    float* out     = (float*)d_out;

    k1<<<BATCH, 256, 0, stream>>>(x, w1, pooled1, p1sum, p1sq);
    k_bnfin<<<8, 256, 0, stream>>>(p1sum, p1sq, g1, b1, s1, sh1,
                                   1.f / (float)((size_t)BATCH * 1024));
    k3<<<BATCH / 4, 256, 0, stream>>>(pooled1, w2, s1, sh1, pooled2, p2sum, p2sq);
    k_bnfin<<<16, 256, 0, stream>>>(p2sum, p2sq, g2, b2, s2, sh2,
                                    1.f / (float)((size_t)BATCH * 256));
    k5<<<BATCH / 4, 256, 0, stream>>>(pooled2, s2, sh2, fcw, fcb, outbuf);
    k67<<<16, 256, 0, stream>>>(outbuf, g3, b3, out);
}

// Round 10
// 288.145 us; speedup vs baseline: 1.3691x; 1.3691x over previous
//
#include <hip/hip_runtime.h>
#include <math.h>

#define EPS_F 1e-5f
static constexpr int BATCH = 4096;

// ---------------------------------------------------------------------------
// K1: conv1 3x3 SAME (1->8) per batch element + bn1 stats (pre-pool) + 2x2
// maxpool of RAW conv output. Pooling in-register via shuffles.
__global__ __launch_bounds__(256) void k1(const float* __restrict__ x,
                                          const float* __restrict__ w1,
                                          float* __restrict__ pooled1,
                                          float* __restrict__ p1sum,
                                          float* __restrict__ p1sq) {
    __shared__ __align__(16) float xs[34 * 34];
    __shared__ float w1s[72];
    __shared__ __align__(16) float ps[2048];
    __shared__ float rsum[4][8], rsq[4][8];

    const int b = blockIdx.x, t = threadIdx.x;
    for (int j = t; j < 34 * 34; j += 256) xs[j] = 0.f;
    if (t < 72) w1s[t] = w1[t];
    __syncthreads();
    {
        float4 v4 = reinterpret_cast<const float4*>(x + (size_t)b * 1024)[t];
        int e = t * 4, y = e >> 5, xx = e & 31;
        float* d = &xs[(y + 1) * 34 + xx + 1];
        d[0] = v4.x; d[1] = v4.y; d[2] = v4.z; d[3] = v4.w;
    }
    __syncthreads();

    const int col = t & 31, y0 = t >> 5;
    float acc[4][8];
#pragma unroll
    for (int k = 0; k < 4; ++k)
#pragma unroll
        for (int c = 0; c < 8; ++c) acc[k][c] = 0.f;

#pragma unroll
    for (int ky = 0; ky < 3; ++ky)
#pragma unroll
        for (int kx = 0; kx < 3; ++kx) {
            float w[8];
#pragma unroll
            for (int c = 0; c < 8; ++c) w[c] = w1s[c * 9 + ky * 3 + kx];
#pragma unroll
            for (int k = 0; k < 4; ++k) {
                float xv = xs[(y0 + 8 * k + ky) * 34 + col + kx];
#pragma unroll
                for (int c = 0; c < 8; ++c) acc[k][c] = fmaf(w[c], xv, acc[k][c]);
            }
        }

    float s[8], q[8];
#pragma unroll
    for (int c = 0; c < 8; ++c) { s[c] = 0.f; q[c] = 0.f; }
#pragma unroll
    for (int k = 0; k < 4; ++k)
#pragma unroll
        for (int c = 0; c < 8; ++c) { s[c] += acc[k][c]; q[c] += acc[k][c] * acc[k][c]; }
#pragma unroll
    for (int d = 1; d < 64; d <<= 1)
#pragma unroll
        for (int c = 0; c < 8; ++c) {
            s[c] += __shfl_xor(s[c], d, 64);
            q[c] += __shfl_xor(q[c], d, 64);
        }
    const int wid = t >> 6, lane = t & 63;
    if (lane == 0)
#pragma unroll
        for (int c = 0; c < 8; ++c) { rsum[wid][c] = s[c]; rsq[wid][c] = q[c]; }

    // 2x2 maxpool in-register: vertical pair lane^32 (y0 parity), horiz lane^1.
#pragma unroll
    for (int k = 0; k < 4; ++k)
#pragma unroll
        for (int c = 0; c < 8; ++c) {
            float vm = fmaxf(acc[k][c], __shfl_xor(acc[k][c], 32, 64));
            float hm = fmaxf(vm, __shfl_xor(vm, 1, 64));
            if ((lane & 33) == 0)
                ps[c * 256 + (4 * k + wid) * 16 + (col >> 1)] = hm;
        }
    __syncthreads();

    if (t < 8) {
        p1sum[t * BATCH + b] = rsum[0][t] + rsum[1][t] + rsum[2][t] + rsum[3][t];
        p1sq [t * BATCH + b] = rsq [0][t] + rsq [1][t] + rsq [2][t] + rsq [3][t];
    }
    float4 o0 = *reinterpret_cast<const float4*>(&ps[t * 8]);
    float4 o1 = *reinterpret_cast<const float4*>(&ps[t * 8 + 4]);
    float4* dst = reinterpret_cast<float4*>(&pooled1[(size_t)b * 2048 + t * 8]);
    dst[0] = o0; dst[1] = o1;
}

// ---------------------------------------------------------------------------
__global__ __launch_bounds__(256) void k_bnfin(const float* __restrict__ psum,
                                               const float* __restrict__ psq,
                                               const float* __restrict__ g,
                                               const float* __restrict__ beta,
                                               float* __restrict__ scale,
                                               float* __restrict__ shift,
                                               float invN) {
    const int ch = blockIdx.x, t = threadIdx.x;
    float s = 0.f, q = 0.f;
    for (int i = t; i < BATCH; i += 256) {
        s += psum[ch * BATCH + i];
        q += psq [ch * BATCH + i];
    }
    __shared__ float rs[256], rq[256];
    rs[t] = s; rq[t] = q;
    __syncthreads();
    for (int d = 128; d > 0; d >>= 1) {
        if (t < d) { rs[t] += rs[t + d]; rq[t] += rq[t + d]; }
        __syncthreads();
    }
    if (t == 0) {
        float mean = rs[0] * invN;
        float var  = rq[0] * invN - mean * mean;
        float sc   = g[ch] * rsqrtf(var + EPS_F);
        scale[ch] = sc;
        shift[ch] = beta[ch] - mean * sc;
    }
}

// ---------------------------------------------------------------------------
// bn2-stats + 2x2 pool + store for ONE oc. acc = 16 x-values at row y.
// Stats reduce over the 16 y-lanes of the aligned lane-group (shfl_xor d<16);
// vertical pool pair is lane^1 (y parity). Transient state: 8 regs.
__device__ __forceinline__ void k3_fin(const float* acc, int oc, int b, int y,
                                       float* __restrict__ pooled2,
                                       float* __restrict__ p2sum,
                                       float* __restrict__ p2sq) {
    float s = 0.f, q = 0.f;
#pragma unroll
    for (int xx = 0; xx < 16; ++xx) { s += acc[xx]; q += acc[xx] * acc[xx]; }
#pragma unroll
    for (int d = 1; d < 16; d <<= 1) { s += __shfl_xor(s, d, 64); q += __shfl_xor(q, d, 64); }
    float pm[8];
#pragma unroll
    for (int px = 0; px < 8; ++px) {
        float v0 = fmaxf(acc[2 * px],     __shfl_xor(acc[2 * px],     1, 64));
        float v1 = fmaxf(acc[2 * px + 1], __shfl_xor(acc[2 * px + 1], 1, 64));
        pm[px] = fmaxf(v0, v1);
    }
    if ((y & 1) == 0) {
        float4* d2 = reinterpret_cast<float4*>(
            &pooled2[(size_t)b * 1024 + oc * 64 + (y >> 1) * 8]);
        d2[0] = make_float4(pm[0], pm[1], pm[2], pm[3]);
        d2[1] = make_float4(pm[4], pm[5], pm[6], pm[7]);
    }
    if (y == 0) { p2sum[oc * BATCH + b] = s; p2sq[oc * BATCH + b] = q; }
}

// ---------------------------------------------------------------------------
// K3: bn1+relu on pooled1raw, conv2 3x3 SAME (8->16), bn2 stats (pre-pool),
// 2x2 maxpool of RAW conv2.
// Layout: 2 elements/block, 2 waves/element; thread owns 2 oc x 16 x for one
// row y (32 acc regs -- the round-8 4-oc version hit 256 VGPR and spilled,
// 241 us from scratch traffic; this halves live state to stay ~130 VGPR).
// Weights pre-transposed in LDS to [ic,ky,kx][oc] so an oc-pair is one b64.
__global__ __launch_bounds__(256) void k3(const float* __restrict__ pooled1,
                                          const float* __restrict__ w2,
                                          const float* __restrict__ s1,
                                          const float* __restrict__ sh1,
                                          float* __restrict__ pooled2,
                                          float* __restrict__ p2sum,
                                          float* __restrict__ p2sq) {
    __shared__ __align__(16) float a1s[2][2880];   // [ic][y+1][x+1], stride 20 (23 KB)
    __shared__ __align__(16) float w2t[1152];      // [(ic*9+ky*3+kx)*16 + oc] (4.6 KB)
    const int t = threadIdx.x;
    const int e = t >> 7;                 // element in block (0..1)
    const int te = t & 127;               // thread within element
    const int lane = t & 63;
    const int wv = (t >> 6) & 1;          // wave within element
    const int o = lane >> 4, y = lane & 15;
    const int ocp = wv * 4 + o;           // oc-pair 0..7 -> ocs {2*ocp, 2*ocp+1}
    const int b = blockIdx.x * 2 + e;

    {   // zero padded tiles (1440 float4)
        float4 z = make_float4(0.f, 0.f, 0.f, 0.f);
        float* base = &a1s[0][0];
        for (int j = t; j < 1440; j += 256)
            *reinterpret_cast<float4*>(&base[j * 4]) = z;
    }
    for (int j = t; j < 1152; j += 256) {   // transpose weights
        int oc = j / 72, r = j - oc * 72;   // r = ic*9 + ky*3 + kx
        w2t[r * 16 + oc] = w2[j];
    }
    __syncthreads();

    float s1r[8], sh1r[8];
#pragma unroll
    for (int c = 0; c < 8; ++c) { s1r[c] = s1[c]; sh1r[c] = sh1[c]; }

    {   // stage own element's interior with bn1+relu (c = i>>1 is static)
        const float* src = pooled1 + (size_t)b * 2048;
        float* dstp = &a1s[e][0];
#pragma unroll
        for (int i = 0; i < 16; ++i) {
            int idx = i * 128 + te;
            int c = i >> 1;
            int rem = idx & 255, py = rem >> 4, px = rem & 15;
            float v = fmaxf(fmaf(src[idx], s1r[c], sh1r[c]), 0.f);
            dstp[c * 360 + (py + 1) * 20 + (px + 1)] = v;
        }
    }
    __syncthreads();

    float accA[16], accB[16];
#pragma unroll
    for (int i = 0; i < 16; ++i) { accA[i] = 0.f; accB[i] = 0.f; }

#pragma unroll
    for (int ic = 0; ic < 8; ++ic)
#pragma unroll
        for (int ky = 0; ky < 3; ++ky) {
            const float* row = &a1s[e][ic * 360 + (y + ky) * 20];
            float r[20];
#pragma unroll
            for (int j = 0; j < 5; ++j)
                *reinterpret_cast<float4*>(&r[4 * j]) =
                    *reinterpret_cast<const float4*>(&row[4 * j]);
#pragma unroll
            for (int kx = 0; kx < 3; ++kx) {
                float2 wp = *reinterpret_cast<const float2*>(
                    &w2t[(ic * 9 + ky * 3 + kx) * 16 + ocp * 2]);
#pragma unroll
                for (int xx = 0; xx < 16; ++xx) {
                    float rv = r[xx + kx];
                    accA[xx] = fmaf(wp.x, rv, accA[xx]);
                    accB[xx] = fmaf(wp.y, rv, accB[xx]);
                }
            }
        }

    k3_fin(accA, ocp * 2 + 0, b, y, pooled2, p2sum, p2sq);
    k3_fin(accB, ocp * 2 + 1, b, y, pooled2, p2sum, p2sq);
}

// ---------------------------------------------------------------------------
// K5: bn2+relu on pooled2raw, encode = mean, circuit collapsed to
// q = (cos e, cos e, cos^2 e, cos^2 e), then fc. One wave per element.
__global__ __launch_bounds__(256) void k5(const float* __restrict__ pooled2,
                                          const float* __restrict__ s2,
                                          const float* __restrict__ sh2,
                                          const float* __restrict__ fcw,
                                          const float* __restrict__ fcb,
                                          float* __restrict__ outbuf) {
    const int t = threadIdx.x, lane = t & 63;
    const int b = blockIdx.x * 4 + (t >> 6);
    const float* p = pooled2 + (size_t)b * 1024;
    float sum = 0.f;
#pragma unroll
    for (int i = 0; i < 16; ++i) {
        float v = p[i * 64 + lane];
        v = fmaxf(fmaf(v, s2[i], sh2[i]), 0.f);
        sum += v;
    }
#pragma unroll
    for (int d = 1; d < 64; d <<= 1) sum += __shfl_xor(sum, d, 64);
    if (lane < 4) {
        float e = sum * (1.f / 1024.f);
        float z = cosf(e), z2 = z * z;
        int j = lane;
        float o = fcb[j] + z * (fcw[j * 4 + 0] + fcw[j * 4 + 1])
                         + z2 * (fcw[j * 4 + 2] + fcw[j * 4 + 3]);
        outbuf[(size_t)b * 4 + j] = o;
    }
}

// ---------------------------------------------------------------------------
// K67: bn3 stats + apply, fused. 16 blocks compute stats redundantly
// (outbuf is 64 KB, L2-resident) then apply to their slice.
__global__ __launch_bounds__(256) void k67(const float* __restrict__ outbuf,
                                           const float* __restrict__ g3,
                                           const float* __restrict__ b3,
                                           float* __restrict__ out) {
    const int t = threadIdx.x, j = t & 3;
    float s = 0.f, q = 0.f;
    for (int i = t >> 2; i < BATCH; i += 64) {
        float v = outbuf[i * 4 + j];
        s += v; q += v * v;
    }
    __shared__ float rs[256], rq[256];
    __shared__ float sc[4], sh[4];
    rs[t] = s; rq[t] = q;
    __syncthreads();
    for (int d = 128; d >= 4; d >>= 1) {
        if (t < d) { rs[t] += rs[t + d]; rq[t] += rq[t + d]; }
        __syncthreads();
    }
    if (t < 4) {
        float mean = rs[t] * (1.f / BATCH);
        float var  = rq[t] * (1.f / BATCH) - mean * mean;
        float s3   = g3[t] * rsqrtf(var + EPS_F);
        sc[t] = s3;
        sh[t] = b3[t] - mean * s3;
    }
    __syncthreads();
    int base = blockIdx.x * 1024 + t * 4;
    float4 v = *reinterpret_cast<const float4*>(&outbuf[base]);
    float4 r;
    r.x = fmaf(v.x, sc[0], sh[0]);
    r.y = fmaf(v.y, sc[1], sh[1]);
    r.z = fmaf(v.z, sc[2], sh[2]);
    r.w = fmaf(v.w, sc[3], sh[3]);
    *reinterpret_cast<float4*>(&out[base]) = r;
}

extern "C" void kernel_launch(void* const* d_in, const int* in_sizes, int n_in,
                              void* d_out, int out_size, void* d_ws, size_t ws_size,
                              hipStream_t stream) {
    const float* x   = (const float*)d_in[0];
    const float* w1  = (const float*)d_in[1];
    // d_in[2] conv1_b: cancels in bn1
    const float* g1  = (const float*)d_in[3];
    const float* b1  = (const float*)d_in[4];
    const float* w2  = (const float*)d_in[5];
    // d_in[6] conv2_b: cancels in bn2
    const float* g2  = (const float*)d_in[7];
    const float* b2  = (const float*)d_in[8];
    // d_in[9] rz_angles: diagonal phases, cancel in probabilities
    const float* fcw = (const float*)d_in[10];
    const float* fcb = (const float*)d_in[11];
    const float* g3  = (const float*)d_in[12];
    const float* b3  = (const float*)d_in[13];

    float* ws      = (float*)d_ws;
    float* pooled1 = ws;                                 // 4096*2048
    float* pooled2 = pooled1 + (size_t)BATCH * 2048;     // 4096*1024
    float* p1sum   = pooled2 + (size_t)BATCH * 1024;     // 8*4096
    float* p1sq    = p1sum + 8 * BATCH;
    float* p2sum   = p1sq  + 8 * BATCH;                  // 16*4096
    float* p2sq    = p2sum + 16 * BATCH;
    float* s1      = p2sq  + 16 * BATCH;                 // 8
    float* sh1     = s1 + 8;
    float* s2      = sh1 + 8;                            // 16
    float* sh2     = s2 + 16;
    float* outbuf  = sh2 + 16;                           // 4096*4
    float* out     = (float*)d_out;

    k1<<<BATCH, 256, 0, stream>>>(x, w1, pooled1, p1sum, p1sq);
    k_bnfin<<<8, 256, 0, stream>>>(p1sum, p1sq, g1, b1, s1, sh1,
                                   1.f / (float)((size_t)BATCH * 1024));
    k3<<<BATCH / 2, 256, 0, stream>>>(pooled1, w2, s1, sh1, pooled2, p2sum, p2sq);
    k_bnfin<<<16, 256, 0, stream>>>(p2sum, p2sq, g2, b2, s2, sh2,
                                    1.f / (float)((size_t)BATCH * 256));
    k5<<<BATCH / 4, 256, 0, stream>>>(pooled2, s2, sh2, fcw, fcb, outbuf);
    k67<<<16, 256, 0, stream>>>(outbuf, g3, b3, out);
}

// Round 14
// 203.434 us; speedup vs baseline: 1.9392x; 1.4164x over previous
//
#include <hip/hip_runtime.h>
#include <math.h>

#define EPS_F 1e-5f
static constexpr int BATCH = 4096;

// ---------------------------------------------------------------------------
// K1: conv1 3x3 SAME (1->8) per batch element + bn1 stats (pre-pool) + 2x2
// maxpool of RAW conv output. Pooling in-register via shuffles.
__global__ __launch_bounds__(256) void k1(const float* __restrict__ x,
                                          const float* __restrict__ w1,
                                          float* __restrict__ pooled1,
                                          float* __restrict__ p1sum,
                                          float* __restrict__ p1sq) {
    __shared__ __align__(16) float xs[34 * 34];
    __shared__ float w1s[72];
    __shared__ __align__(16) float ps[2048];
    __shared__ float rsum[4][8], rsq[4][8];

    const int b = blockIdx.x, t = threadIdx.x;
    for (int j = t; j < 34 * 34; j += 256) xs[j] = 0.f;
    if (t < 72) w1s[t] = w1[t];
    __syncthreads();
    {
        float4 v4 = reinterpret_cast<const float4*>(x + (size_t)b * 1024)[t];
        int e = t * 4, y = e >> 5, xx = e & 31;
        float* d = &xs[(y + 1) * 34 + xx + 1];
        d[0] = v4.x; d[1] = v4.y; d[2] = v4.z; d[3] = v4.w;
    }
    __syncthreads();

    const int col = t & 31, y0 = t >> 5;
    float acc[4][8];
#pragma unroll
    for (int k = 0; k < 4; ++k)
#pragma unroll
        for (int c = 0; c < 8; ++c) acc[k][c] = 0.f;

#pragma unroll
    for (int ky = 0; ky < 3; ++ky)
#pragma unroll
        for (int kx = 0; kx < 3; ++kx) {
            float w[8];
#pragma unroll
            for (int c = 0; c < 8; ++c) w[c] = w1s[c * 9 + ky * 3 + kx];
#pragma unroll
            for (int k = 0; k < 4; ++k) {
                float xv = xs[(y0 + 8 * k + ky) * 34 + col + kx];
#pragma unroll
                for (int c = 0; c < 8; ++c) acc[k][c] = fmaf(w[c], xv, acc[k][c]);
            }
        }

    float s[8], q[8];
#pragma unroll
    for (int c = 0; c < 8; ++c) { s[c] = 0.f; q[c] = 0.f; }
#pragma unroll
    for (int k = 0; k < 4; ++k)
#pragma unroll
        for (int c = 0; c < 8; ++c) { s[c] += acc[k][c]; q[c] += acc[k][c] * acc[k][c]; }
#pragma unroll
    for (int d = 1; d < 64; d <<= 1)
#pragma unroll
        for (int c = 0; c < 8; ++c) {
            s[c] += __shfl_xor(s[c], d, 64);
            q[c] += __shfl_xor(q[c], d, 64);
        }
    const int wid = t >> 6, lane = t & 63;
    if (lane == 0)
#pragma unroll
        for (int c = 0; c < 8; ++c) { rsum[wid][c] = s[c]; rsq[wid][c] = q[c]; }

    // 2x2 maxpool in-register: vertical pair lane^32 (y0 parity), horiz lane^1.
#pragma unroll
    for (int k = 0; k < 4; ++k)
#pragma unroll
        for (int c = 0; c < 8; ++c) {
            float vm = fmaxf(acc[k][c], __shfl_xor(acc[k][c], 32, 64));
            float hm = fmaxf(vm, __shfl_xor(vm, 1, 64));
            if ((lane & 33) == 0)
                ps[c * 256 + (4 * k + wid) * 16 + (col >> 1)] = hm;
        }
    __syncthreads();

    if (t < 8) {
        p1sum[t * BATCH + b] = rsum[0][t] + rsum[1][t] + rsum[2][t] + rsum[3][t];
        p1sq [t * BATCH + b] = rsq [0][t] + rsq [1][t] + rsq [2][t] + rsq [3][t];
    }
    float4 o0 = *reinterpret_cast<const float4*>(&ps[t * 8]);
    float4 o1 = *reinterpret_cast<const float4*>(&ps[t * 8 + 4]);
    float4* dst = reinterpret_cast<float4*>(&pooled1[(size_t)b * 2048 + t * 8]);
    dst[0] = o0; dst[1] = o1;
}

// ---------------------------------------------------------------------------
__global__ __launch_bounds__(256) void k_bnfin(const float* __restrict__ psum,
                                               const float* __restrict__ psq,
                                               const float* __restrict__ g,
                                               const float* __restrict__ beta,
                                               float* __restrict__ scale,
                                               float* __restrict__ shift,
                                               float invN) {
    const int ch = blockIdx.x, t = threadIdx.x;
    float s = 0.f, q = 0.f;
    for (int i = t; i < BATCH; i += 256) {
        s += psum[ch * BATCH + i];
        q += psq [ch * BATCH + i];
    }
    __shared__ float rs[256], rq[256];
    rs[t] = s; rq[t] = q;
    __syncthreads();
    for (int d = 128; d > 0; d >>= 1) {
        if (t < d) { rs[t] += rs[t + d]; rq[t] += rq[t + d]; }
        __syncthreads();
    }
    if (t == 0) {
        float mean = rs[0] * invN;
        float var  = rq[0] * invN - mean * mean;
        float sc   = g[ch] * rsqrtf(var + EPS_F);
        scale[ch] = sc;
        shift[ch] = beta[ch] - mean * sc;
    }
}

// ---------------------------------------------------------------------------
// bn2-stats + 2x2 pool + store for ONE oc. acc = 16 x-values at row y.
// Stats reduce over the 16 y-lanes of the aligned lane-group (shfl_xor d<16);
// vertical pool pair is lane^1 (y parity). Transient state: 8 regs.
__device__ __forceinline__ void k3_fin(const float* acc, int oc, int b, int y,
                                       float* __restrict__ pooled2,
                                       float* __restrict__ p2sum,
                                       float* __restrict__ p2sq) {
    float s = 0.f, q = 0.f;
#pragma unroll
    for (int xx = 0; xx < 16; ++xx) { s += acc[xx]; q += acc[xx] * acc[xx]; }
#pragma unroll
    for (int d = 1; d < 16; d <<= 1) { s += __shfl_xor(s, d, 64); q += __shfl_xor(q, d, 64); }
    float pm[8];
#pragma unroll
    for (int px = 0; px < 8; ++px) {
        float v0 = fmaxf(acc[2 * px],     __shfl_xor(acc[2 * px],     1, 64));
        float v1 = fmaxf(acc[2 * px + 1], __shfl_xor(acc[2 * px + 1], 1, 64));
        pm[px] = fmaxf(v0, v1);
    }
    if ((y & 1) == 0) {
        float4* d2 = reinterpret_cast<float4*>(
            &pooled2[(size_t)b * 1024 + oc * 64 + (y >> 1) * 8]);
        d2[0] = make_float4(pm[0], pm[1], pm[2], pm[3]);
        d2[1] = make_float4(pm[4], pm[5], pm[6], pm[7]);
    }
    if (y == 0) { p2sum[oc * BATCH + b] = s; p2sq[oc * BATCH + b] = q; }
}

// ---------------------------------------------------------------------------
// K3: bn1+relu on pooled1raw, conv2 3x3 SAME (8->16), bn2 stats (pre-pool),
// 2x2 maxpool of RAW conv2.
// Layout: 2 elements/block, 2 waves/element; thread owns 2 oc x 16 x for one
// row y (32 acc regs).
// Round-10 post-mortem: VGPR still 256 + 187 MB spill-writes -- the fully
// unrolled ic*ky loop let the scheduler hoist ~24 iterations of r[20] LDS
// loads. Fix: __launch_bounds__(256,4) caps the allocator at 128 VGPR, and
// #pragma unroll 1 on the ic loop bounds the scheduling window (ky*3 inner
// unroll keeps 60 r-regs live max; total live ~110 < 128).
__global__ __launch_bounds__(256, 4) void k3(const float* __restrict__ pooled1,
                                             const float* __restrict__ w2,
                                             const float* __restrict__ s1,
                                             const float* __restrict__ sh1,
                                             float* __restrict__ pooled2,
                                             float* __restrict__ p2sum,
                                             float* __restrict__ p2sq) {
    __shared__ __align__(16) float a1s[2][2880];   // [ic][y+1][x+1], stride 20 (23 KB)
    __shared__ __align__(16) float w2t[1152];      // [(ic*9+ky*3+kx)*16 + oc] (4.6 KB)
    const int t = threadIdx.x;
    const int e = t >> 7;                 // element in block (0..1)
    const int te = t & 127;               // thread within element
    const int lane = t & 63;
    const int wv = (t >> 6) & 1;          // wave within element
    const int o = lane >> 4, y = lane & 15;
    const int ocp = wv * 4 + o;           // oc-pair 0..7 -> ocs {2*ocp, 2*ocp+1}
    const int b = blockIdx.x * 2 + e;

    {   // zero padded tiles (1440 float4)
        float4 z = make_float4(0.f, 0.f, 0.f, 0.f);
        float* base = &a1s[0][0];
        for (int j = t; j < 1440; j += 256)
            *reinterpret_cast<float4*>(&base[j * 4]) = z;
    }
    for (int j = t; j < 1152; j += 256) {   // transpose weights
        int oc = j / 72, r = j - oc * 72;   // r = ic*9 + ky*3 + kx
        w2t[r * 16 + oc] = w2[j];
    }
    __syncthreads();

    float s1r[8], sh1r[8];
#pragma unroll
    for (int c = 0; c < 8; ++c) { s1r[c] = s1[c]; sh1r[c] = sh1[c]; }

    {   // stage own element's interior with bn1+relu (c = i>>1 is static)
        const float* src = pooled1 + (size_t)b * 2048;
        float* dstp = &a1s[e][0];
#pragma unroll
        for (int i = 0; i < 16; ++i) {
            int idx = i * 128 + te;
            int c = i >> 1;
            int rem = idx & 255, py = rem >> 4, px = rem & 15;
            float v = fmaxf(fmaf(src[idx], s1r[c], sh1r[c]), 0.f);
            dstp[c * 360 + (py + 1) * 20 + (px + 1)] = v;
        }
    }
    __syncthreads();

    float accA[16], accB[16];
#pragma unroll
    for (int i = 0; i < 16; ++i) { accA[i] = 0.f; accB[i] = 0.f; }

#pragma unroll 1
    for (int ic = 0; ic < 8; ++ic)
#pragma unroll
        for (int ky = 0; ky < 3; ++ky) {
            const float* row = &a1s[e][ic * 360 + (y + ky) * 20];
            float r[20];
#pragma unroll
            for (int j = 0; j < 5; ++j)
                *reinterpret_cast<float4*>(&r[4 * j]) =
                    *reinterpret_cast<const float4*>(&row[4 * j]);
#pragma unroll
            for (int kx = 0; kx < 3; ++kx) {
                float2 wp = *reinterpret_cast<const float2*>(
                    &w2t[(ic * 9 + ky * 3 + kx) * 16 + ocp * 2]);
#pragma unroll
                for (int xx = 0; xx < 16; ++xx) {
                    float rv = r[xx + kx];
                    accA[xx] = fmaf(wp.x, rv, accA[xx]);
                    accB[xx] = fmaf(wp.y, rv, accB[xx]);
                }
            }
        }

    k3_fin(accA, ocp * 2 + 0, b, y, pooled2, p2sum, p2sq);
    k3_fin(accB, ocp * 2 + 1, b, y, pooled2, p2sum, p2sq);
}

// ---------------------------------------------------------------------------
// K5: bn2+relu on pooled2raw, encode = mean, circuit collapsed to
// q = (cos e, cos e, cos^2 e, cos^2 e), then fc. One wave per element.
__global__ __launch_bounds__(256) void k5(const float* __restrict__ pooled2,
                                          const float* __restrict__ s2,
                                          const float* __restrict__ sh2,
                                          const float* __restrict__ fcw,
                                          const float* __restrict__ fcb,
                                          float* __restrict__ outbuf) {
    const int t = threadIdx.x, lane = t & 63;
    const int b = blockIdx.x * 4 + (t >> 6);
    const float* p = pooled2 + (size_t)b * 1024;
    float sum = 0.f;
#pragma unroll
    for (int i = 0; i < 16; ++i) {
        float v = p[i * 64 + lane];
        v = fmaxf(fmaf(v, s2[i], sh2[i]), 0.f);
        sum += v;
    }
#pragma unroll
    for (int d = 1; d < 64; d <<= 1) sum += __shfl_xor(sum, d, 64);
    if (lane < 4) {
        float e = sum * (1.f / 1024.f);
        float z = cosf(e), z2 = z * z;
        int j = lane;
        float o = fcb[j] + z * (fcw[j * 4 + 0] + fcw[j * 4 + 1])
                         + z2 * (fcw[j * 4 + 2] + fcw[j * 4 + 3]);
        outbuf[(size_t)b * 4 + j] = o;
    }
}

// ---------------------------------------------------------------------------
// K67: bn3 stats + apply, fused. 16 blocks compute stats redundantly
// (outbuf is 64 KB, L2-resident) then apply to their slice.
__global__ __launch_bounds__(256) void k67(const float* __restrict__ outbuf,
                                           const float* __restrict__ g3,
                                           const float* __restrict__ b3,
                                           float* __restrict__ out) {
    const int t = threadIdx.x, j = t & 3;
    float s = 0.f, q = 0.f;
    for (int i = t >> 2; i < BATCH; i += 64) {
        float v = outbuf[i * 4 + j];
        s += v; q += v * v;
    }
    __shared__ float rs[256], rq[256];
    __shared__ float sc[4], sh[4];
    rs[t] = s; rq[t] = q;
    __syncthreads();
    for (int d = 128; d >= 4; d >>= 1) {
        if (t < d) { rs[t] += rs[t + d]; rq[t] += rq[t + d]; }
        __syncthreads();
    }
    if (t < 4) {
        float mean = rs[t] * (1.f / BATCH);
        float var  = rq[t] * (1.f / BATCH) - mean * mean;
        float s3   = g3[t] * rsqrtf(var + EPS_F);
        sc[t] = s3;
        sh[t] = b3[t] - mean * s3;
    }
    __syncthreads();
    int base = blockIdx.x * 1024 + t * 4;
    float4 v = *reinterpret_cast<const float4*>(&outbuf[base]);
    float4 r;
    r.x = fmaf(v.x, sc[0], sh[0]);
    r.y = fmaf(v.y, sc[1], sh[1]);
    r.z = fmaf(v.z, sc[2], sh[2]);
    r.w = fmaf(v.w, sc[3], sh[3]);
    *reinterpret_cast<float4*>(&out[base]) = r;
}

extern "C" void kernel_launch(void* const* d_in, const int* in_sizes, int n_in,
                              void* d_out, int out_size, void* d_ws, size_t ws_size,
                              hipStream_t stream) {
    const float* x   = (const float*)d_in[0];
    const float* w1  = (const float*)d_in[1];
    // d_in[2] conv1_b: cancels in bn1
    const float* g1  = (const float*)d_in[3];
    const float* b1  = (const float*)d_in[4];
    const float* w2  = (const float*)d_in[5];
    // d_in[6] conv2_b: cancels in bn2
    const float* g2  = (const float*)d_in[7];
    const float* b2  = (const float*)d_in[8];
    // d_in[9] rz_angles: diagonal phases, cancel in probabilities
    const float* fcw = (const float*)d_in[10];
    const float* fcb = (const float*)d_in[11];
    const float* g3  = (const float*)d_in[12];
    const float* b3  = (const float*)d_in[13];

    float* ws      = (float*)d_ws;
    float* pooled1 = ws;                                 // 4096*2048
    float* pooled2 = pooled1 + (size_t)BATCH * 2048;     // 4096*1024
    float* p1sum   = pooled2 + (size_t)BATCH * 1024;     // 8*4096
    float* p1sq    = p1sum + 8 * BATCH;
    float* p2sum   = p1sq  + 8 * BATCH;                  // 16*4096
    float* p2sq    = p2sum + 16 * BATCH;
    float* s1      = p2sq  + 16 * BATCH;                 // 8
    float* sh1     = s1 + 8;
    float* s2      = sh1 + 8;                            // 16
    float* sh2     = s2 + 16;
    float* outbuf  = sh2 + 16;                           // 4096*4
    float* out     = (float*)d_out;

    k1<<<BATCH, 256, 0, stream>>>(x, w1, pooled1, p1sum, p1sq);
    k_bnfin<<<8, 256, 0, stream>>>(p1sum, p1sq, g1, b1, s1, sh1,
                                   1.f / (float)((size_t)BATCH * 1024));
    k3<<<BATCH / 2, 256, 0, stream>>>(pooled1, w2, s1, sh1, pooled2, p2sum, p2sq);
    k_bnfin<<<16, 256, 0, stream>>>(p2sum, p2sq, g2, b2, s2, sh2,
                                    1.f / (float)((size_t)BATCH * 256));
    k5<<<BATCH / 4, 256, 0, stream>>>(pooled2, s2, sh2, fcw, fcb, outbuf);
    k67<<<16, 256, 0, stream>>>(outbuf, g3, b3, out);
}

// Round 15
// 197.429 us; speedup vs baseline: 1.9982x; 1.0304x over previous
//
#include <hip/hip_runtime.h>
#include <math.h>

#define EPS_F 1e-5f
static constexpr int BATCH = 4096;

// ---------------------------------------------------------------------------
// K1: conv1 3x3 SAME (1->8) per batch element + bn1 stats (pre-pool) + 2x2
// maxpool of RAW conv output.
// R14 rewrite: thread = (col, yb) owns 4 consecutive rows 4yb..4yb+3 so the
// vertical pool pair is IN-REGISTER (pool shfls 64->16/thread), and the bn1
// stats use a channel-folding reduction (xor32/16/8 fold 8ch->1, then 3-level
// butterfly: 20 shfls vs 96). ds_bpermute is an LDS-pipe op on CDNA, so
// cutting shfl count cuts LDS pressure directly.
__global__ __launch_bounds__(256) void k1(const float* __restrict__ x,
                                          const float* __restrict__ w1,
                                          float* __restrict__ pooled1,
                                          float* __restrict__ p1sum,
                                          float* __restrict__ p1sq) {
    __shared__ __align__(16) float xs[34 * 34];
    __shared__ float w1s[72];
    __shared__ __align__(16) float ps[2048];
    __shared__ float rsum[4][8], rsq[4][8];

    const int b = blockIdx.x, t = threadIdx.x;
    for (int j = t; j < 34 * 34; j += 256) xs[j] = 0.f;
    if (t < 72) w1s[t] = w1[t];
    __syncthreads();
    {
        float4 v4 = reinterpret_cast<const float4*>(x + (size_t)b * 1024)[t];
        int e = t * 4, y = e >> 5, xx = e & 31;
        float* d = &xs[(y + 1) * 34 + xx + 1];
        d[0] = v4.x; d[1] = v4.y; d[2] = v4.z; d[3] = v4.w;
    }
    __syncthreads();

    const int col = t & 31, yb = t >> 5;   // yb 0..7 -> rows 4yb..4yb+3
    float acc[4][8];
#pragma unroll
    for (int i = 0; i < 4; ++i)
#pragma unroll
        for (int c = 0; c < 8; ++c) acc[i][c] = 0.f;

#pragma unroll
    for (int ky = 0; ky < 3; ++ky)
#pragma unroll
        for (int kx = 0; kx < 3; ++kx) {
            float w[8];
#pragma unroll
            for (int c = 0; c < 8; ++c) w[c] = w1s[c * 9 + ky * 3 + kx];
#pragma unroll
            for (int i = 0; i < 4; ++i) {
                float xv = xs[(4 * yb + i + ky) * 34 + col + kx];
#pragma unroll
                for (int c = 0; c < 8; ++c) acc[i][c] = fmaf(w[c], xv, acc[i][c]);
            }
        }

    // per-thread stats partials (4 rows x 1 col, 8 ch)
    float s[8], q[8];
#pragma unroll
    for (int c = 0; c < 8; ++c) { s[c] = 0.f; q[c] = 0.f; }
#pragma unroll
    for (int i = 0; i < 4; ++i)
#pragma unroll
        for (int c = 0; c < 8; ++c) { s[c] += acc[i][c]; q[c] += acc[i][c] * acc[i][c]; }

    const int l = t & 63, wid = t >> 6;
    // fold 8->4 (xor 32): partners share all higher fold bits, so local
    // channel numbering stays consistent.
    {
        const bool hi = (l & 32) != 0;
        float fs[4], fq[4];
#pragma unroll
        for (int c = 0; c < 4; ++c) { fs[c] = hi ? s[c] : s[c + 4]; fq[c] = hi ? q[c] : q[c + 4]; }
#pragma unroll
        for (int c = 0; c < 4; ++c) {
            float ys = __shfl_xor(fs[c], 32, 64);
            float yq = __shfl_xor(fq[c], 32, 64);
            s[c] = (hi ? s[c + 4] : s[c]) + ys;
            q[c] = (hi ? q[c + 4] : q[c]) + yq;
        }
    }
    // fold 4->2 (xor 16)
    {
        const bool hi = (l & 16) != 0;
        float fs[2], fq[2];
#pragma unroll
        for (int c = 0; c < 2; ++c) { fs[c] = hi ? s[c] : s[c + 2]; fq[c] = hi ? q[c] : q[c + 2]; }
#pragma unroll
        for (int c = 0; c < 2; ++c) {
            float ys = __shfl_xor(fs[c], 16, 64);
            float yq = __shfl_xor(fq[c], 16, 64);
            s[c] = (hi ? s[c + 2] : s[c]) + ys;
            q[c] = (hi ? q[c + 2] : q[c]) + yq;
        }
    }
    // fold 2->1 (xor 8)
    {
        const bool hi = (l & 8) != 0;
        float fs = hi ? s[0] : s[1];
        float fq = hi ? q[0] : q[1];
        float ys = __shfl_xor(fs, 8, 64);
        float yq = __shfl_xor(fq, 8, 64);
        s[0] = (hi ? s[1] : s[0]) + ys;
        q[0] = (hi ? q[1] : q[0]) + yq;
    }
    // butterfly over remaining 8 lanes (xor 4,2,1)
#pragma unroll
    for (int d = 4; d > 0; d >>= 1) {
        s[0] += __shfl_xor(s[0], d, 64);
        q[0] += __shfl_xor(q[0], d, 64);
    }
    if ((l & 7) == 0) { rsum[wid][l >> 3] = s[0]; rsq[wid][l >> 3] = q[0]; }

    // 2x2 pool: vertical pair in-register, horizontal via lane^1 (col parity)
#pragma unroll
    for (int j = 0; j < 2; ++j)
#pragma unroll
        for (int c = 0; c < 8; ++c) {
            float vm = fmaxf(acc[2 * j][c], acc[2 * j + 1][c]);
            float hm = fmaxf(vm, __shfl_xor(vm, 1, 64));
            if ((col & 1) == 0)
                ps[c * 256 + (2 * yb + j) * 16 + (col >> 1)] = hm;
        }
    __syncthreads();

    if (t < 8) {
        p1sum[t * BATCH + b] = rsum[0][t] + rsum[1][t] + rsum[2][t] + rsum[3][t];
        p1sq [t * BATCH + b] = rsq [0][t] + rsq [1][t] + rsq [2][t] + rsq [3][t];
    }
    float4 o0 = *reinterpret_cast<const float4*>(&ps[t * 8]);
    float4 o1 = *reinterpret_cast<const float4*>(&ps[t * 8 + 4]);
    float4* dst = reinterpret_cast<float4*>(&pooled1[(size_t)b * 2048 + t * 8]);
    dst[0] = o0; dst[1] = o1;
}

// ---------------------------------------------------------------------------
__global__ __launch_bounds__(256) void k_bnfin(const float* __restrict__ psum,
                                               const float* __restrict__ psq,
                                               const float* __restrict__ g,
                                               const float* __restrict__ beta,
                                               float* __restrict__ scale,
                                               float* __restrict__ shift,
                                               float invN) {
    const int ch = blockIdx.x, t = threadIdx.x;
    float s = 0.f, q = 0.f;
    for (int i = t; i < BATCH; i += 256) {
        s += psum[ch * BATCH + i];
        q += psq [ch * BATCH + i];
    }
    __shared__ float rs[256], rq[256];
    rs[t] = s; rq[t] = q;
    __syncthreads();
    for (int d = 128; d > 0; d >>= 1) {
        if (t < d) { rs[t] += rs[t + d]; rq[t] += rq[t + d]; }
        __syncthreads();
    }
    if (t == 0) {
        float mean = rs[0] * invN;
        float var  = rq[0] * invN - mean * mean;
        float sc   = g[ch] * rsqrtf(var + EPS_F);
        scale[ch] = sc;
        shift[ch] = beta[ch] - mean * sc;
    }
}

// ---------------------------------------------------------------------------
// bn2-stats + 2x2 pool + store for ONE oc. acc = 16 x-values at row y.
__device__ __forceinline__ void k3_fin(const float* acc, int oc, int b, int y,
                                       float* __restrict__ pooled2,
                                       float* __restrict__ p2sum,
                                       float* __restrict__ p2sq) {
    float s = 0.f, q = 0.f;
#pragma unroll
    for (int xx = 0; xx < 16; ++xx) { s += acc[xx]; q += acc[xx] * acc[xx]; }
#pragma unroll
    for (int d = 1; d < 16; d <<= 1) { s += __shfl_xor(s, d, 64); q += __shfl_xor(q, d, 64); }
    float pm[8];
#pragma unroll
    for (int px = 0; px < 8; ++px) {
        float v0 = fmaxf(acc[2 * px],     __shfl_xor(acc[2 * px],     1, 64));
        float v1 = fmaxf(acc[2 * px + 1], __shfl_xor(acc[2 * px + 1], 1, 64));
        pm[px] = fmaxf(v0, v1);
    }
    if ((y & 1) == 0) {
        float4* d2 = reinterpret_cast<float4*>(
            &pooled2[(size_t)b * 1024 + oc * 64 + (y >> 1) * 8]);
        d2[0] = make_float4(pm[0], pm[1], pm[2], pm[3]);
        d2[1] = make_float4(pm[4], pm[5], pm[6], pm[7]);
    }
    if (y == 0) { p2sum[oc * BATCH + b] = s; p2sq[oc * BATCH + b] = q; }
}

// ---------------------------------------------------------------------------
// K3: bn1+relu on pooled1raw, conv2 3x3 SAME (8->16), bn2 stats (pre-pool),
// 2x2 maxpool of RAW conv2. 2 elems/block, 2 waves/elem, 2 oc x 16 x /thread.
// R14: w2t transpose now DEST-linear (r=j>>4, oc=j&15) -- the source-linear
// form wrote stride-16-dword addresses (banks {0,16} only, ~32-way conflict).
// Dest-linear writes are consecutive dwords -> conflict-free; the strided
// w2 reads hit L2 (4.6 KB resident).
__global__ __launch_bounds__(256, 4) void k3(const float* __restrict__ pooled1,
                                             const float* __restrict__ w2,
                                             const float* __restrict__ s1,
                                             const float* __restrict__ sh1,
                                             float* __restrict__ pooled2,
                                             float* __restrict__ p2sum,
                                             float* __restrict__ p2sq) {
    __shared__ __align__(16) float a1s[2][2880];   // [ic][y+1][x+1], stride 20 (23 KB)
    __shared__ __align__(16) float w2t[1152];      // [(ic*9+ky*3+kx)*16 + oc] (4.6 KB)
    const int t = threadIdx.x;
    const int e = t >> 7;
    const int te = t & 127;
    const int lane = t & 63;
    const int wv = (t >> 6) & 1;
    const int o = lane >> 4, y = lane & 15;
    const int ocp = wv * 4 + o;
    const int b = blockIdx.x * 2 + e;

    {   // zero padded tiles (1440 float4)
        float4 z = make_float4(0.f, 0.f, 0.f, 0.f);
        float* base = &a1s[0][0];
        for (int j = t; j < 1440; j += 256)
            *reinterpret_cast<float4*>(&base[j * 4]) = z;
    }
    for (int j = t; j < 1152; j += 256) {   // transpose weights, dest-linear
        int r = j >> 4, oc = j & 15;        // r = ic*9 + ky*3 + kx
        w2t[j] = w2[oc * 72 + r];
    }
    __syncthreads();

    float s1r[8], sh1r[8];
#pragma unroll
    for (int c = 0; c < 8; ++c) { s1r[c] = s1[c]; sh1r[c] = sh1[c]; }

    {   // stage own element's interior with bn1+relu (c = i>>1 is static)
        const float* src = pooled1 + (size_t)b * 2048;
        float* dstp = &a1s[e][0];
#pragma unroll
        for (int i = 0; i < 16; ++i) {
            int idx = i * 128 + te;
            int c = i >> 1;
            int rem = idx & 255, py = rem >> 4, px = rem & 15;
            float v = fmaxf(fmaf(src[idx], s1r[c], sh1r[c]), 0.f);
            dstp[c * 360 + (py + 1) * 20 + (px + 1)] = v;
        }
    }
    __syncthreads();

    float accA[16], accB[16];
#pragma unroll
    for (int i = 0; i < 16; ++i) { accA[i] = 0.f; accB[i] = 0.f; }

#pragma unroll 1
    for (int ic = 0; ic < 8; ++ic)
#pragma unroll
        for (int ky = 0; ky < 3; ++ky) {
            const float* row = &a1s[e][ic * 360 + (y + ky) * 20];
            float r[20];
#pragma unroll
            for (int j = 0; j < 5; ++j)
                *reinterpret_cast<float4*>(&r[4 * j]) =
                    *reinterpret_cast<const float4*>(&row[4 * j]);
#pragma unroll
            for (int kx = 0; kx < 3; ++kx) {
                float2 wp = *reinterpret_cast<const float2*>(
                    &w2t[(ic * 9 + ky * 3 + kx) * 16 + ocp * 2]);
#pragma unroll
                for (int xx = 0; xx < 16; ++xx) {
                    float rv = r[xx + kx];
                    accA[xx] = fmaf(wp.x, rv, accA[xx]);
                    accB[xx] = fmaf(wp.y, rv, accB[xx]);
                }
            }
        }

    k3_fin(accA, ocp * 2 + 0, b, y, pooled2, p2sum, p2sq);
    k3_fin(accB, ocp * 2 + 1, b, y, pooled2, p2sum, p2sq);
}

// ---------------------------------------------------------------------------
// K5: bn2+relu on pooled2raw, encode = mean, circuit collapsed to
// q = (cos e, cos e, cos^2 e, cos^2 e), then fc. One wave per element.
__global__ __launch_bounds__(256) void k5(const float* __restrict__ pooled2,
                                          const float* __restrict__ s2,
                                          const float* __restrict__ sh2,
                                          const float* __restrict__ fcw,
                                          const float* __restrict__ fcb,
                                          float* __restrict__ outbuf) {
    const int t = threadIdx.x, lane = t & 63;
    const int b = blockIdx.x * 4 + (t >> 6);
    const float* p = pooled2 + (size_t)b * 1024;
    float sum = 0.f;
#pragma unroll
    for (int i = 0; i < 16; ++i) {
        float v = p[i * 64 + lane];
        v = fmaxf(fmaf(v, s2[i], sh2[i]), 0.f);
        sum += v;
    }
#pragma unroll
    for (int d = 1; d < 64; d <<= 1) sum += __shfl_xor(sum, d, 64);
    if (lane < 4) {
        float e = sum * (1.f / 1024.f);
        float z = cosf(e), z2 = z * z;
        int j = lane;
        float o = fcb[j] + z * (fcw[j * 4 + 0] + fcw[j * 4 + 1])
                         + z2 * (fcw[j * 4 + 2] + fcw[j * 4 + 3]);
        outbuf[(size_t)b * 4 + j] = o;
    }
}

// ---------------------------------------------------------------------------
// K67: bn3 stats + apply, fused. 16 blocks compute stats redundantly
// (outbuf is 64 KB, L2-resident) then apply to their slice.
__global__ __launch_bounds__(256) void k67(const float* __restrict__ outbuf,
                                           const float* __restrict__ g3,
                                           const float* __restrict__ b3,
                                           float* __restrict__ out) {
    const int t = threadIdx.x, j = t & 3;
    float s = 0.f, q = 0.f;
    for (int i = t >> 2; i < BATCH; i += 64) {
        float v = outbuf[i * 4 + j];
        s += v; q += v * v;
    }
    __shared__ float rs[256], rq[256];
    __shared__ float sc[4], sh[4];
    rs[t] = s; rq[t] = q;
    __syncthreads();
    for (int d = 128; d >= 4; d >>= 1) {
        if (t < d) { rs[t] += rs[t + d]; rq[t] += rq[t + d]; }
        __syncthreads();
    }
    if (t < 4) {
        float mean = rs[t] * (1.f / BATCH);
        float var  = rq[t] * (1.f / BATCH) - mean * mean;
        float s3   = g3[t] * rsqrtf(var + EPS_F);
        sc[t] = s3;
        sh[t] = b3[t] - mean * s3;
    }
    __syncthreads();
    int base = blockIdx.x * 1024 + t * 4;
    float4 v = *reinterpret_cast<const float4*>(&outbuf[base]);
    float4 r;
    r.x = fmaf(v.x, sc[0], sh[0]);
    r.y = fmaf(v.y, sc[1], sh[1]);
    r.z = fmaf(v.z, sc[2], sh[2]);
    r.w = fmaf(v.w, sc[3], sh[3]);
    *reinterpret_cast<float4*>(&out[base]) = r;
}

extern "C" void kernel_launch(void* const* d_in, const int* in_sizes, int n_in,
                              void* d_out, int out_size, void* d_ws, size_t ws_size,
                              hipStream_t stream) {
    const float* x   = (const float*)d_in[0];
    const float* w1  = (const float*)d_in[1];
    // d_in[2] conv1_b: cancels in bn1
    const float* g1  = (const float*)d_in[3];
    const float* b1  = (const float*)d_in[4];
    const float* w2  = (const float*)d_in[5];
    // d_in[6] conv2_b: cancels in bn2
    const float* g2  = (const float*)d_in[7];
    const float* b2  = (const float*)d_in[8];
    // d_in[9] rz_angles: diagonal phases, cancel in probabilities
    const float* fcw = (const float*)d_in[10];
    const float* fcb = (const float*)d_in[11];
    const float* g3  = (const float*)d_in[12];
    const float* b3  = (const float*)d_in[13];

    float* ws      = (float*)d_ws;
    float* pooled1 = ws;                                 // 4096*2048
    float* pooled2 = pooled1 + (size_t)BATCH * 2048;     // 4096*1024
    float* p1sum   = pooled2 + (size_t)BATCH * 1024;     // 8*4096
    float* p1sq    = p1sum + 8 * BATCH;
    float* p2sum   = p1sq  + 8 * BATCH;                  // 16*4096
    float* p2sq    = p2sum + 16 * BATCH;
    float* s1      = p2sq  + 16 * BATCH;                 // 8
    float* sh1     = s1 + 8;
    float* s2      = sh1 + 8;                            // 16
    float* sh2     = s2 + 16;
    float* outbuf  = sh2 + 16;                           // 4096*4
    float* out     = (float*)d_out;

    k1<<<BATCH, 256, 0, stream>>>(x, w1, pooled1, p1sum, p1sq);
    k_bnfin<<<8, 256, 0, stream>>>(p1sum, p1sq, g1, b1, s1, sh1,
                                   1.f / (float)((size_t)BATCH * 1024));
    k3<<<BATCH / 2, 256, 0, stream>>>(pooled1, w2, s1, sh1, pooled2, p2sum, p2sq);
    k_bnfin<<<16, 256, 0, stream>>>(p2sum, p2sq, g2, b2, s2, sh2,
                                    1.f / (float)((size_t)BATCH * 256));
    k5<<<BATCH / 4, 256, 0, stream>>>(pooled2, s2, sh2, fcw, fcb, outbuf);
    k67<<<16, 256, 0, stream>>>(outbuf, g3, b3, out);
}